// Round 12
// baseline (882.990 us; speedup 1.0000x reference)
//
#include <hip/hip_runtime.h>

// Seq2Seq LSTM (enc 512 + dec 256 steps), H=50, B=2048, in/out dim 1.
//
// Round-23: TWO INDEPENDENT single-wave chains per SIMD. r20's 1463cy step
// = 541cy MFMA pipe (floor) + ~900cy act/DS/latency with the pipe IDLE.
// Scheduling attempts inside one wave all failed (r14 neutral, r21/r22
// regressed) -> single-wave dependence floor reached. Fix: occupancy-level
// overlap. MB=1 per wave (1 batch, 1 cell/lane), 128-thread blocks = 2
// waves, grid 1024 -> 2 waves/SIMD. Wave B's 32 MFMAs fill the pipe while
// wave A runs its act tail; SIMD round-robins issue; MFMA/VALU separate
// pipes (m114). s_sleep staggers wave 1 half a step; backpressure then
// self-stabilizes anti-phase. Steady step ~= max(chain ~900, 2x515 pipe)
// ~= 1030-1150cy.
//  - 1 cell/lane: act = 16 static sums + 3-cndmask select/gate + 4 sigm
//    + 1 tanh (~60 ops, chain ~300cy << 515).  [rule-#20-safe: all
//    register indices static; runtime select via ternary -> cndmask]
//  - h layout: identity permutation (pos = unit), hs[wave][buf][split][64];
//    reads 2xb128 (2-way bank alias, free), writes 2xb16 (2 lanes/bank).
//  - A-rows m: split = m&1, 8x dup; D sums = acc[0](s0) + acc[1](s1).
//  - decoder: in-lane fc + 6-stage 64-lane butterfly; direct y store
//    (fire-and-forget, no barrier/vmcnt drains anywhere).
// Math identical to r20 (absmax 4.88e-4): fp16 weights (rel 2^-11),
// fp16-split h (h=h0+h1), L2E folded, g-gate doubled -> tanh via sigm.
//
// Fragment maps (verified r10-r22): A[m=lane&15][k=(lane>>4)*8+j],
// B[n=lane&15][k=kt*32+(lane>>4)*8+j], D col=lane&15, row=4*(lane>>4)+reg.

#define HID 50
#define SEQ 512
#define TGT 256
#define L2E 1.44269504088896341f

typedef __attribute__((ext_vector_type(8))) _Float16 half8;
typedef __attribute__((ext_vector_type(4))) float f32x4;

#define MFMA16(A, B, C) __builtin_amdgcn_mfma_f32_16x16x32_f16((A), (B), (C), 0, 0, 0)

// One LSTM step for ONE batch (this wave). 1 cell/lane. Reads h from
// hs[w][IB], writes h' to hs[w][OB]. XV enters at the sum stage (post-MFMA
// -> decoder feedback off the gemv path). Updates cc; defines hv.
#define GSTEP(XV, IB, OB)                                                   \
    {                                                                       \
        const _Float16* hp_ = &hs[w][IB][sA][0];                            \
        half8 a0 = *(const half8*)(hp_ + kg * 8);        /* k 0..31  */     \
        half8 a1 = *(const half8*)(hp_ + 32 + kg * 8);   /* k 32..63 */     \
        f32x4 acc[16];                                                      \
        _Pragma("unroll")                                                   \
        for (int j = 0; j < 16; ++j) {                                      \
            f32x4 z = {0.0f, 0.0f, 0.0f, 0.0f};                             \
            z = MFMA16(a0, Bw[j][0], z);                                    \
            z = MFMA16(a1, Bw[j][1], z);                                    \
            acc[j] = z;                                                     \
        }                                                                   \
        float sums[16];                                                     \
        _Pragma("unroll")                                                   \
        for (int j = 0; j < 16; ++j)                                        \
            sums[j] = acc[j][0] + acc[j][1];      /* s0-row + s1-row */     \
        float xv_ = (XV);                                                   \
        float sm[4], R_[4];                                                 \
        _Pragma("unroll")                                                   \
        for (int g = 0; g < 4; ++g) {            /* select ug = kg */       \
            float s01 = (kg & 1) ? sums[g * 4 + 1] : sums[g * 4 + 0];       \
            float s23 = (kg & 1) ? sums[g * 4 + 3] : sums[g * 4 + 2];       \
            float sg  = (kg & 2) ? s23 : s01;                               \
            sm[g] = sg + fmaf(wx[g], xv_, bb[g]);                           \
        }                                                                   \
        _Pragma("unroll")                                                   \
        for (int g = 0; g < 4; ++g)                                         \
            R_[g] = __builtin_amdgcn_rcpf(1.0f +                            \
                        __builtin_amdgcn_exp2f(-sm[g]));                    \
        float vg = fmaf(2.0f, R_[2], -1.0f);     /* tanh via sigm */        \
        cc = fmaf(R_[1], cc, R_[0] * vg);                                   \
        float r2 = __builtin_amdgcn_rcpf(1.0f +                             \
                       __builtin_amdgcn_exp2f(-2.0f * L2E * cc));           \
        hv = R_[3] * fmaf(2.0f, r2, -1.0f);                                 \
        _Float16 q0 = (_Float16)hv;                                         \
        _Float16 q1 = (_Float16)(hv - (float)q0);                           \
        hs[w][OB][0][u] = q0;                     /* split0 */              \
        hs[w][OB][1][u] = q1;                     /* split1 */              \
    }

// Decoder step: GSTEP + in-lane fc + 64-lane butterfly; direct y store.
#define DSTEP(T, IB, OB)                                                    \
    {                                                                       \
        GSTEP(xc, IB, OB)                                                   \
        float p = fcw * hv;                                                 \
        p += __shfl_xor(p, 1, 64);                                          \
        p += __shfl_xor(p, 2, 64);                                          \
        p += __shfl_xor(p, 4, 64);                                          \
        p += __shfl_xor(p, 8, 64);                                          \
        p += __shfl_xor(p, 16, 64);                                         \
        p += __shfl_xor(p, 32, 64);                                         \
        float y = p + fb;                                                   \
        if (lane == 0) out[(size_t)b * TGT + (T)] = y;                      \
        xc = y;                                                             \
    }

extern "C" __global__ void __launch_bounds__(128, 2)
seq2seq_kernel(const float* __restrict__ src,
               const float* __restrict__ eWih, const float* __restrict__ eWhh,
               const float* __restrict__ eBih, const float* __restrict__ eBhh,
               const float* __restrict__ dWih, const float* __restrict__ dWhh,
               const float* __restrict__ dBih, const float* __restrict__ dBhh,
               const float* __restrict__ fcW, const float* __restrict__ fcB,
               float* __restrict__ out) {
    const int tid  = threadIdx.x;        // 0..127
    const int w    = tid >> 6;           // wave 0/1 = independent batch
    const int lane = tid & 63;
    const int c    = lane & 15;          // D col / A row m
    const int kg   = lane >> 4;          // A/B k-octet; selects ugroup
    const int sA   = c & 1;              // A-row m -> h split (m&1)
    const int u    = kg * 16 + c;        // this lane's unit
    const int b    = blockIdx.x * 2 + w; // this wave's batch

    // hs[wave][buf][split][64 units]; per-wave disjoint -> no barrier ever
    __shared__ __align__(16) _Float16 hs[2][2][2][64];
    __shared__ __align__(16) float srcT[2][SEQ];

    // per-wave zero + stage (own regions only)
    for (int i = lane; i < 2 * 2 * 64 / 2; i += 64) ((int*)&hs[w])[i] = 0;
    for (int i = lane; i < SEQ; i += 64)
        srcT[w][i] = src[(size_t)b * SEQ + i];

    half8 Bw[16][2];                     // [tile=(g*4+ug)][kt] fp16 weights
    float wx[4], bb[4];                  // this cell's x-weights / bias
    float cc = 0.0f, hv;

    auto loadW = [&](const float* Wih, const float* Whh,
                     const float* Bih, const float* Bhh) {
#pragma unroll
        for (int j = 0; j < 16; ++j) {
            const int g  = j >> 2, ug = j & 3;             // tile=(gate,ug)
            const int uo = ug * 16 + c;                    // output unit
            const bool uv = (uo < HID);
            const float sc = (g == 2) ? 2.0f * L2E : L2E;  // tanh fold
            const int row = g * HID + (uv ? uo : 0);       // PyTorch g*50+u
#pragma unroll
            for (int kt = 0; kt < 2; ++kt) {
                half8 s0;
#pragma unroll
                for (int jj = 0; jj < 8; ++jj) {
                    int k = kt * 32 + kg * 8 + jj;         // pos = unit
                    float wv = (uv && k < HID)
                             ? Whh[(size_t)row * HID + k] * sc : 0.0f;
                    s0[jj] = (_Float16)wv;
                }
                Bw[j][kt] = s0;
            }
        }
#pragma unroll
        for (int g = 0; g < 4; ++g) {                      // my cell u
            const bool uv = (u < HID);
            const float sc = (g == 2) ? 2.0f * L2E : L2E;
            const int row = g * HID + (uv ? u : 0);
            wx[g] = uv ? Wih[row] * sc : 0.0f;
            bb[g] = uv ? (Bih[row] + Bhh[row]) * sc : 0.0f;
        }
    };

    // ---------------- encoder: 512 steps (x2 unroll, h dbuf) -------------
    loadW(eWih, eWhh, eBih, eBhh);
    if (w == 1) __builtin_amdgcn_s_sleep(7);   // ~450cy anti-phase stagger
    for (int t = 0; t < SEQ; t += 2) {
        float2 xp = *(const float2*)&srcT[w][t];
        { GSTEP(xp.x, 0, 1) }
        { GSTEP(xp.y, 1, 0) }
    }
    // h(512) in buf 0; cc persists in registers

    // ---------------- decoder: 256 steps (x2 unroll) ---------------------
    loadW(dWih, dWhh, dBih, dBhh);
    const float fcw = (u < HID) ? fcW[u] : 0.0f;
    const float fb  = fcB[0];
    float xc = 0.0f;                     // decoder_input = zeros
    for (int t = 0; t < TGT; t += 2) {
        DSTEP(t,     0, 1)
        DSTEP(t + 1, 1, 0)
    }
}

extern "C" void kernel_launch(void* const* d_in, const int* in_sizes, int n_in,
                              void* d_out, int out_size, void* d_ws, size_t ws_size,
                              hipStream_t stream) {
    const float* src  = (const float*)d_in[0];
    const float* eWih = (const float*)d_in[1];
    const float* eWhh = (const float*)d_in[2];
    const float* eBih = (const float*)d_in[3];
    const float* eBhh = (const float*)d_in[4];
    const float* dWih = (const float*)d_in[5];
    const float* dWhh = (const float*)d_in[6];
    const float* dBih = (const float*)d_in[7];
    const float* dBhh = (const float*)d_in[8];
    const float* fcW  = (const float*)d_in[9];
    const float* fcB  = (const float*)d_in[10];
    float* out = (float*)d_out;

    const int B = in_sizes[0] / SEQ;     // 2048
    seq2seq_kernel<<<B / 2, 128, 0, stream>>>(src, eWih, eWhh, eBih, eBhh,
                                              dWih, dWhh, dBih, dBhh,
                                              fcW, fcB, out);
}